// Round 12
// baseline (589.807 us; speedup 1.0000x reference)
//
#include <hip/hip_runtime.h>
#include <hip/hip_bf16.h>

// Shapes (fixed): B=16, L=1024, C=512, P=64, H=8, DK=64, MRD=7
#define BI   16
#define LSEQ 1024
#define CDIM 512
#define PDIM 64
#define HH   8
#define DKK  64

typedef __hip_bfloat16 bf16;
typedef unsigned short u16;
typedef __attribute__((ext_vector_type(8))) short bf16x8;
typedef __attribute__((ext_vector_type(4))) float f32x4;

// rel-pos bucket boundaries: bucket t covers |l-m| in [dlo[t], dhi[t]]
__constant__ int c_dlo[15] = {0,1,2,3,4,5,6,7, 9,11,15,23,39, 71,135};
__constant__ int c_dhi[15] = {0,1,2,3,4,5,6,8,10,14,22,38,70,134,1023};

__device__ __forceinline__ float b2f(u16 u) {
    union { unsigned int i; float f; } c; c.i = ((unsigned int)u) << 16; return c.f;
}
__device__ __forceinline__ u16 f2bu(float v) {
    bf16 h = __float2bfloat16(v);
    return *(u16*)&h;
}
// dynamic-dtype loads: f=1 -> fp32, f=0 -> bf16
__device__ __forceinline__ float ldDyn(const void* p, size_t i, int f) {
    return f ? ((const float*)p)[i] : b2f(((const u16*)p)[i]);
}
__device__ __forceinline__ void ld4Dyn(const void* p, size_t i, int f, float* o) {
    if (f) { float4 v = *(const float4*)((const float*)p + i);
             o[0]=v.x; o[1]=v.y; o[2]=v.z; o[3]=v.w; }
    else   { ushort4 u = *(const ushort4*)((const u16*)p + i);
             o[0]=b2f(u.x); o[1]=b2f(u.y); o[2]=b2f(u.z); o[3]=b2f(u.w); }
}

// async global->LDS, 16B/lane; lds base wave-uniform (HW: base + lane*16)
__device__ __forceinline__ void gll16(const u16* g, u16* l) {
    __builtin_amdgcn_global_load_lds(
        (const __attribute__((address_space(1))) unsigned int*)g,
        (__attribute__((address_space(3))) unsigned int*)l,
        16, 0, 0);
}

__device__ __forceinline__ float wsum(float v) {
    #pragma unroll
    for (int o = 32; o; o >>= 1) v += __shfl_xor(v, o, 64);
    return v;
}
__device__ __forceinline__ float wmax(float v) {
    #pragma unroll
    for (int o = 32; o; o >>= 1) v = fmaxf(v, __shfl_xor(v, o, 64));
    return v;
}

// exact-precision gelu: erf via Abramowitz-Stegun 7.1.26 (max abs err 1.5e-7)
__device__ __forceinline__ float gelu_f(float v) {
    float x  = v * 0.70710678118654752f;
    float ax = fabsf(x);
    float t  = __builtin_amdgcn_rcpf(1.0f + 0.3275911f * ax);
    float p  = t * (0.254829592f + t * (-0.284496736f + t * (1.421413741f +
               t * (-1.453152027f + t * 1.061405429f))));
    float e  = __expf(-ax * ax);
    float er = 1.0f - p * e;
    er = (x < 0.0f) ? -er : er;
    return 0.5f * v * (1.0f + er);
}

// ---------------------------------------------------------------------------
// dtype detect: flag 0 = bf16, 1 = fp32
// ---------------------------------------------------------------------------
__global__ void k_detect(const unsigned int* __restrict__ qw, int* __restrict__ flag) {
    __shared__ int cnt;
    if (threadIdx.x == 0) cnt = 0;
    __syncthreads();
    int local = 0;
    for (int i = threadIdx.x; i < 4096; i += 256) {
        float fv = b2f((u16)(qw[i] & 0xFFFFu));
        float af = fabsf(fv);
        if (fv == 0.0f || (af >= 0.0009765625f && af <= 32.0f)) local++;
    }
    atomicAdd(&cnt, local);
    __syncthreads();
    if (threadIdx.x == 0) flag[0] = (cnt >= 2048) ? 0 : 1;
}

// ---------------------------------------------------------------------------
// fused 2-tensor convert -> bf16 flat (y selects pair)
// ---------------------------------------------------------------------------
__global__ __launch_bounds__(256) void k_cvt2(
    const void* __restrict__ s0, u16* __restrict__ d0,
    const void* __restrict__ s1, u16* __restrict__ d1,
    const int* __restrict__ flag, int n)
{
    const int fA = flag[0];
    const void* src = blockIdx.y ? s1 : s0;
    u16* dst = blockIdx.y ? d1 : d0;
    int i = (blockIdx.x * 256 + threadIdx.x) * 4;
    if (i >= n) return;
    float t[4]; ld4Dyn(src, i, fA, t);
    ushort4 o; o.x = f2bu(t[0]); o.y = f2bu(t[1]); o.z = f2bu(t[2]); o.w = f2bu(t[3]);
    *(ushort4*)(dst + i) = o;
}

// ---------------------------------------------------------------------------
// transpose dyn W[Kd][Nd] -> bf16 WT[Nd][Kd]
// ---------------------------------------------------------------------------
__device__ __forceinline__ void transp_core(
    const void* W, u16* WT, int fd, int Kd, int Nd, int bx, int by)
{
    __shared__ u16 t[32][33];
    const int tx = threadIdx.x & 31, ty = threadIdx.x >> 5;   // 32 x 8
    #pragma unroll
    for (int r = 0; r < 32; r += 8) {
        int k = by * 32 + ty + r, n = bx * 32 + tx;
        t[ty + r][tx] = f2bu(ldDyn(W, (size_t)k * Nd + n, fd));
    }
    __syncthreads();
    #pragma unroll
    for (int r = 0; r < 32; r += 8) {
        int n = bx * 32 + ty + r, k = by * 32 + tx;
        WT[(size_t)n * Kd + k] = t[tx][ty + r];
    }
}

__global__ __launch_bounds__(256) void k_transp(
    const void* __restrict__ W, u16* __restrict__ WT, const int* __restrict__ flag,
    int Kd, int Nd)
{
    transp_core(W, WT, flag[0], Kd, Nd, blockIdx.x, blockIdx.y);
}

// fused 4x 512x512 transpose (z selects weight)
__global__ __launch_bounds__(256) void k_transp4(
    const void* __restrict__ W0, u16* __restrict__ T0,
    const void* __restrict__ W1, u16* __restrict__ T1,
    const void* __restrict__ W2, u16* __restrict__ T2,
    const void* __restrict__ W3, u16* __restrict__ T3,
    const int* __restrict__ flag)
{
    const void* W; u16* T;
    switch (blockIdx.z) {
        case 0: W = W0; T = T0; break;
        case 1: W = W1; T = T1; break;
        case 2: W = W2; T = T2; break;
        default: W = W3; T = T3; break;
    }
    transp_core(W, T, flag[0], 512, 512, blockIdx.x, blockIdx.y);
}

// ---------------------------------------------------------------------------
// transpose+convert activations: src (B,L,C) -> dst (B,C,L) bf16
// z<16: kx (dyn dtype); z>=16: vxb (bf16). Tiles: 32 c-rows x 64 l-cols.
// ---------------------------------------------------------------------------
__global__ __launch_bounds__(256) void k_transpcv(
    const void* __restrict__ kx, const u16* __restrict__ vxb,
    u16* __restrict__ kxT, u16* __restrict__ vxT, const int* __restrict__ flag)
{
    const int t = blockIdx.z >> 4;        // 0=k, 1=v
    const int b = blockIdx.z & 15;
    const int l0 = blockIdx.x * 64, c0 = blockIdx.y * 32;
    __shared__ u16 s[32][72];             // [c][l], padded
    const int tid = threadIdx.x;
    if (t == 0) {
        const int fd = flag[0];
        #pragma unroll
        for (int p = 0; p < 2; ++p) {
            int l = (tid >> 3) + p * 32, c4 = (tid & 7) * 4;
            float v[4];
            ld4Dyn(kx, ((size_t)b * LSEQ + l0 + l) * CDIM + c0 + c4, fd, v);
            #pragma unroll
            for (int k = 0; k < 4; ++k) s[c4 + k][l] = f2bu(v[k]);
        }
    } else {
        #pragma unroll
        for (int p = 0; p < 2; ++p) {
            int l = (tid >> 3) + p * 32, c4 = (tid & 7) * 4;
            ushort4 u = *(const ushort4*)&vxb[((size_t)b * LSEQ + l0 + l) * CDIM + c0 + c4];
            s[c4 + 0][l] = u.x; s[c4 + 1][l] = u.y;
            s[c4 + 2][l] = u.z; s[c4 + 3][l] = u.w;
        }
    }
    __syncthreads();
    u16* dst = t ? vxT : kxT;
    #pragma unroll
    for (int p = 0; p < 2; ++p) {
        int c = (tid >> 4) + p * 16, l4 = (tid & 15) * 4;
        *(ushort4*)&dst[((size_t)b * CDIM + c0 + c) * LSEQ + l0 + l4] =
            *(const ushort4*)&s[c][l4];
    }
}

// ---------------------------------------------------------------------------
// MFMA bf16 GEMM core: 128m x 256n tile, BK=64, 8 waves (512 thr), each wave
// a 64x64 sub-tile (4x4 16x16x32 frags, 2 k-halves per step = 32 MFMA/iter).
// Same verified 2-buf two-barrier counted-vmcnt schedule as R7/R9/R11, but
// each K-step covers 64 k-cols -> HALF the steps, same sync per step:
//   iter t: stage(t+1) [6 gll16/lane] -> vmcnt(6) [tile t landed, t+1 in
//   flight] -> s_barrier -> ds_read+MFMA (h=0,1) buf t&1 -> lgkmcnt(0)+barrier.
// LDS 96 KB (As 32 + Bs 64) -> 1 block/CU; occupancy is not the limiter
// (R11 evidence: FFN1@24 waves/CU == FFN2@8 waves/CU rate).
// T2 swizzle for 128-B rows: LDS 16B-chunk c of row r holds global chunk
// c ^ (r&7); stage source col = ((lane&7)^(lane>>3))*8 u16 (LDS write linear
// per gll16 HW); read chunk = (h*4+q) ^ (l16&7). Involution: read returns
// global chunk (g^(r&7))^(r&7) = g. Banks: bank = (row*128 + chunk*16)/4 %32
// = (chunk*4+word)%32 (row term vanishes) -> 8 distinct chunks over 16 lanes
// = 2 lanes/bank-slot = free (m136).
// mode 0: C = acc+bias ; 1: C = gelu(acc+bias) ;
// mode 2: C = acc + bias + bf16 residual res[m*ldc+col] (outBf selects dtype)
// perm=1 (modes 0/1): write at ((m>>6)<<15)+(col<<6)+(m&63)
// ---------------------------------------------------------------------------
__device__ __forceinline__ void gemm_core(
    u16 (*As)[64], u16 (*Bs)[64],
    const u16* A, const u16* BT, const void* bias, const u16* res, void* Cc, int fd,
    int K, int lda, int ldbt, int ldc, size_t bOff, int mode, int outBf, int perm,
    int m0, int n0)
{
    const int tid = threadIdx.x;
    const int wave = tid >> 6, lane = tid & 63;
    const int q = lane >> 4, l16 = lane & 15;
    const int wm = (wave >> 2) * 64, wn = (wave & 3) * 64;
    const int r8 = lane >> 3;                          // stage row within 8-group
    const int sc64 = ((lane & 7) ^ r8) * 8;            // swizzled source col (u16)
    const int rswz = l16 & 7;                          // read-side row XOR
    const int nt = K >> 6;

    f32x4 acc[4][4];
    #pragma unroll
    for (int i = 0; i < 4; ++i)
        #pragma unroll
        for (int j = 0; j < 4; ++j) acc[i][j] = (f32x4){0.f, 0.f, 0.f, 0.f};

    // 6 gll16 per lane per stage call (A: 128x64 = 2; B: 256x64 = 4).
    // Each gll16: wave's 64 lanes fill 8 rows x 8 chunks (1 KB) linearly.
    auto stage = [&](int t, int buf) {
        #pragma unroll
        for (int p = 0; p < 2; ++p)
            gll16(A + (size_t)(m0 + wave * 16 + p * 8 + r8) * lda + t * 64 + sc64,
                  &As[buf * 128 + wave * 16 + p * 8][0]);
        #pragma unroll
        for (int p = 0; p < 2; ++p)
            #pragma unroll
            for (int s = 0; s < 2; ++s)
                gll16(BT + (size_t)(n0 + p * 128 + wave * 16 + s * 8 + r8) * ldbt + t * 64 + sc64,
                      &Bs[buf * 256 + p * 128 + wave * 16 + s * 8][0]);
    };

    stage(0, 0);

    for (int t = 0; t < nt; ++t) {
        if (t + 1 < nt) {
            stage(t + 1, (t + 1) & 1);
            asm volatile("s_waitcnt vmcnt(6)" ::: "memory");   // tile t landed
        } else {
            asm volatile("s_waitcnt vmcnt(0)" ::: "memory");
        }
        __builtin_amdgcn_sched_barrier(0);
        __builtin_amdgcn_s_barrier();          // all waves: tile t staged

        const int ca = (t & 1) * 128, cbB = (t & 1) * 256;
        #pragma unroll
        for (int h = 0; h < 2; ++h) {          // two K=32 halves of the 64-col tile
            const int chq = ((h * 4 + q) ^ rswz) * 8;
            bf16x8 af[4], bfr[4];
            #pragma unroll
            for (int i = 0; i < 4; ++i)
                af[i] = *(const bf16x8*)&As[ca + wm + i * 16 + l16][chq];
            #pragma unroll
            for (int j = 0; j < 4; ++j)
                bfr[j] = *(const bf16x8*)&Bs[cbB + wn + j * 16 + l16][chq];
            #pragma unroll
            for (int i = 0; i < 4; ++i)
                #pragma unroll
                for (int j = 0; j < 4; ++j)
                    acc[i][j] = __builtin_amdgcn_mfma_f32_16x16x32_bf16(af[i], bfr[j], acc[i][j], 0, 0, 0);
        }

        if (t + 1 < nt) {
            // my ds_reads of buf t are complete -> safe for all to restage it
            asm volatile("s_waitcnt lgkmcnt(0)" ::: "memory");
            __builtin_amdgcn_sched_barrier(0);
            __builtin_amdgcn_s_barrier();
        }
    }

    // hoisted bias: depends only on (j, l16)
    float bv[4];
    #pragma unroll
    for (int j = 0; j < 4; ++j)
        bv[j] = ldDyn(bias, bOff + (size_t)(n0 + wn + j * 16 + l16), fd);

    #pragma unroll
    for (int i = 0; i < 4; ++i) {
        int row = m0 + wm + i * 16 + q * 4;
        #pragma unroll
        for (int j = 0; j < 4; ++j) {
            int col = n0 + wn + j * 16 + l16;
            #pragma unroll
            for (int r = 0; r < 4; ++r) {
                float v = acc[i][j][r] + bv[j];
                int m = row + r;
                if (mode == 2) {
                    v += b2f(res[(size_t)m * ldc + col]);
                    if (outBf) ((u16*)Cc)[(size_t)m * ldc + col] = f2bu(v);
                    else       ((float*)Cc)[(size_t)m * ldc + col] = v;
                } else {
                    if (mode == 1) v = gelu_f(v);
                    size_t idx = perm ? (size_t)((m >> 6) << 15) + ((size_t)col << 6) + (m & 63)
                                      : (size_t)m * ldc + col;
                    if (outBf) ((u16*)Cc)[idx] = f2bu(v);
                    else       ((float*)Cc)[idx] = v;
                }
            }
        }
    }
}

// XCD-aware bijective swizzle (nwg multiple of 8): each XCD gets a contiguous
// chunk of M-panels so A-panels + weights fit its private L2.
__global__ __launch_bounds__(512) void gemm_mfma(
    const u16* __restrict__ A, const u16* __restrict__ BT, const void* __restrict__ bias,
    const u16* __restrict__ res, void* __restrict__ Cc, const int* __restrict__ flag,
    int K, int lda, int ldbt, int ldc, size_t bOff, int mode, int outBf, int perm)
{
    __shared__ u16 As[256][64];   // 2 x 128-row bufs, 32 KB
    __shared__ u16 Bs[512][64];   // 2 x 256-row bufs, 64 KB
    const int lin = blockIdx.y * gridDim.x + blockIdx.x;
    const int chunk = (gridDim.x * gridDim.y) >> 3;
    const int wg = (lin & 7) * chunk + (lin >> 3);
    const int bx = wg % gridDim.x, by = wg / gridDim.x;
    gemm_core(As, Bs, A, BT, bias, res, Cc, flag[0], K, lda, ldbt, ldc, bOff,
              mode, outBf, perm, by * 128, bx * 256);
}

// ---------------------------------------------------------------------------
// Merged q-projection + k/v projection in ONE launch, grid (2, 144):
//   by <  128 : q-proj (256 blocks, XCD-swizzled over the q-subgrid)
//   by >= 128 : kv (16 blocks: t = by-128; z = t>>3 selects k/v; M-tile = t&7)
// Both paths call the same gemm_core with K=512 -> identical, block-uniform
// barrier structure (branch is on blockIdx only; no divergent barriers).
// ---------------------------------------------------------------------------
__global__ __launch_bounds__(512) void gemm_qkv(
    const u16* __restrict__ Aq, const u16* __restrict__ WqT,
    const void* __restrict__ bQ, u16* __restrict__ qz,
    const u16* __restrict__ A0, const u16* __restrict__ A1,
    const u16* __restrict__ BT0, const u16* __restrict__ BT1,
    const void* __restrict__ b0, const void* __restrict__ b1,
    void* __restrict__ C0, void* __restrict__ C1,
    const int* __restrict__ flag)
{
    __shared__ u16 As[256][64];
    __shared__ u16 Bs[512][64];
    const int fd = flag[0];
    if (blockIdx.y < 128) {
        const int lin = blockIdx.y * 2 + blockIdx.x;       // 256 q-blocks
        const int wg = (lin & 7) * 32 + (lin >> 3);        // bijective XCD swizzle
        const int bx = wg & 1, by = wg >> 1;
        gemm_core(As, Bs, Aq, WqT, bQ, nullptr, qz, fd,
                  CDIM, CDIM, CDIM, CDIM, 0, 0, 1, 0, by * 128, bx * 256);
    } else {
        const int t = blockIdx.y - 128;                    // 0..15
        const int z = t >> 3, by = t & 7;
        gemm_core(As, Bs, z ? A1 : A0, z ? BT1 : BT0, z ? b1 : b0, nullptr,
                  z ? C1 : C0, fd,
                  CDIM, CDIM, CDIM, CDIM, 0, 0, 1, z ? 1 : 0,
                  by * 128, blockIdx.x * 256);
    }
}

// ---------------------------------------------------------------------------
// MFMA pooling: out[b,p,c] = sum_l pAT[b,p,l] * T[b,c,l]; bf16 out into kvxb.
// M=64 (P), N-tile=128 over C, K=L=1024. Double-buffered.
// ---------------------------------------------------------------------------
__global__ __launch_bounds__(256) void gemm_pool(
    const u16* __restrict__ pAT, const u16* __restrict__ kxT,
    const u16* __restrict__ vxT, u16* __restrict__ kvxb)
{
    __shared__ u16 As[128][32];    // 2 x 64-row bufs
    __shared__ u16 Bs[256][32];    // 2 x 128-row bufs
    const int b = blockIdx.y;
    const int n0 = blockIdx.x * 128;
    const u16* Ag = pAT + (size_t)b * (PDIM * LSEQ);
    const u16* Bg = (blockIdx.z ? vxT : kxT) + (size_t)b * (CDIM * LSEQ);
    u16* Cg = kvxb + (size_t)blockIdx.z * 524288 + (size_t)b * (PDIM * CDIM);

    const int tid = threadIdx.x;
    const int wave = tid >> 6, lane = tid & 63;
    const int q = lane >> 4, l16 = lane & 15;
    const int wm = (wave >> 1) * 32, wn = (wave & 1) * 64;
    const int srow = lane >> 2, scol = (lane & 3) * 8;

    f32x4 acc[2][4];
    #pragma unroll
    for (int i = 0; i < 2; ++i)
        #pragma unroll
        for (int j = 0; j < 4; ++j) acc[i][j] = (f32x4){0.f, 0.f, 0.f, 0.f};

    gll16(Ag + (size_t)(wave * 16 + srow) * LSEQ + scol, &As[wave * 16][0]);
    #pragma unroll
    for (int pass = 0; pass < 2; ++pass)
        gll16(Bg + (size_t)(n0 + wave * 32 + pass * 16 + srow) * LSEQ + scol,
              &Bs[wave * 32 + pass * 16][0]);
    __syncthreads();

    int cur = 0;
    for (int k0 = 0; k0 < LSEQ; k0 += 32) {
        if (k0 + 32 < LSEQ) {
            const int na = (cur ^ 1) * 64, nb = (cur ^ 1) * 128;
            gll16(Ag + (size_t)(wave * 16 + srow) * LSEQ + (k0 + 32) + scol,
                  &As[na + wave * 16][0]);
            #pragma unroll
            for (int pass = 0; pass < 2; ++pass)
                gll16(Bg + (size_t)(n0 + wave * 32 + pass * 16 + srow) * LSEQ + (k0 + 32) + scol,
                      &Bs[nb + wave * 32 + pass * 16][0]);
        }
        const int ca = cur * 64, cb = cur * 128;
        bf16x8 af[2], bfr[4];
        #pragma unroll
        for (int i = 0; i < 2; ++i) af[i] = *(const bf16x8*)&As[ca + wm + i * 16 + l16][q * 8];
        #pragma unroll
        for (int j = 0; j < 4; ++j) bfr[j] = *(const bf16x8*)&Bs[cb + wn + j * 16 + l16][q * 8];
        #pragma unroll
        for (int i = 0; i < 2; ++i)
            #pragma unroll
            for (int j = 0; j < 4; ++j)
                acc[i][j] = __builtin_amdgcn_mfma_f32_16x16x32_bf16(af[i], bfr[j], acc[i][j], 0, 0, 0);
        __syncthreads();
        cur ^= 1;
    }

    #pragma unroll
    for (int i = 0; i < 2; ++i) {
        int row = wm + i * 16 + q * 4;
        #pragma unroll
        for (int j = 0; j < 4; ++j) {
            int col = n0 + wn + j * 16 + l16;
            #pragma unroll
            for (int r = 0; r < 4; ++r)
                Cg[(size_t)(row + r) * CDIM + col] = f2bu(acc[i][j][r]);
        }
    }
}

// ---------------------------------------------------------------------------
// MFMA bf16 GEMM, 128m x 64n tile (pScore): C = A @ BT^T + bias, f32, ldc=64
// Double-buffered.
// ---------------------------------------------------------------------------
__global__ __launch_bounds__(256) void gemm_mfma64(
    const u16* __restrict__ A, const u16* __restrict__ BT, const void* __restrict__ bias,
    float* __restrict__ Cc, const int* __restrict__ flag,
    int K, int lda, int ldbt)
{
    const int fd = flag[0];
    __shared__ u16 As[256][32];    // 2 x 128-row bufs
    __shared__ u16 Bs[128][32];    // 2 x 64-row bufs
    const int m0 = blockIdx.y * 128;
    const int tid = threadIdx.x;
    const int wave = tid >> 6, lane = tid & 63;
    const int q = lane >> 4, l16 = lane & 15;
    const int wm = wave * 32;
    const int srow = wave * 16 + (lane >> 2);
    const int scol = (lane & 3) * 8;

    f32x4 acc[2][4];
    #pragma unroll
    for (int i = 0; i < 2; ++i)
        #pragma unroll
        for (int j = 0; j < 4; ++j) acc[i][j] = (f32x4){0.f, 0.f, 0.f, 0.f};

    #pragma unroll
    for (int pass = 0; pass < 2; ++pass) {
        int row = pass * 64 + srow;
        gll16(A + (size_t)(m0 + row) * lda + scol, &As[pass * 64 + wave * 16][0]);
    }
    gll16(BT + (size_t)srow * ldbt + scol, &Bs[wave * 16][0]);
    __syncthreads();

    int cur = 0;
    for (int k0 = 0; k0 < K; k0 += 32) {
        if (k0 + 32 < K) {
            const int na = (cur ^ 1) * 128, nb = (cur ^ 1) * 64;
            #pragma unroll
            for (int pass = 0; pass < 2; ++pass) {
                int row = pass * 64 + srow;
                gll16(A + (size_t)(m0 + row) * lda + (k0 + 32) + scol,
                      &As[na + pass * 64 + wave * 16][0]);
            }
            gll16(BT + (size_t)srow * ldbt + (k0 + 32) + scol, &Bs[nb + wave * 16][0]);
        }
        const int ca = cur * 128, cb = cur * 64;
        bf16x8 af[2], bfr[4];
        #pragma unroll
        for (int i = 0; i < 2; ++i) af[i] = *(const bf16x8*)&As[ca + wm + i * 16 + l16][q * 8];
        #pragma unroll
        for (int j = 0; j < 4; ++j) bfr[j] = *(const bf16x8*)&Bs[cb + j * 16 + l16][q * 8];
        #pragma unroll
        for (int i = 0; i < 2; ++i)
            #pragma unroll
            for (int j = 0; j < 4; ++j)
                acc[i][j] = __builtin_amdgcn_mfma_f32_16x16x32_bf16(af[i], bfr[j], acc[i][j], 0, 0, 0);
        __syncthreads();
        cur ^= 1;
    }

    #pragma unroll
    for (int i = 0; i < 2; ++i) {
        int row = m0 + wm + i * 16 + q * 4;
        #pragma unroll
        for (int j = 0; j < 4; ++j) {
            int col = j * 16 + l16;
            #pragma unroll
            for (int r = 0; r < 4; ++r)
                Cc[(size_t)(row + r) * 64 + col] = acc[i][j][r] + ldDyn(bias, col, fd);
        }
    }
}

// ---------------------------------------------------------------------------
// Attention GEMMs, batched per (b,h): 128m x 64n, K=64, 4 waves stacked in m.
// mode 0: raw[bh,l,p] = bf16(0.125 * q_h @ k_h^T)  (A=qz lda=512, B=kbh ldb=512)
// mode 1: z[b,l,h*64+d] = alpha_h @ v_h^T          (A=albuf lda=64, B=vbT ldb=64)
// ---------------------------------------------------------------------------
__global__ __launch_bounds__(256) void gemm_att(
    const u16* __restrict__ Abase, const u16* __restrict__ Bbase,
    u16* __restrict__ outp, int mode)
{
    __shared__ u16 Aq[2][128][32];   // [k-half][l][k] 16 KB
    __shared__ u16 Bk[2][64][32];    // 8 KB
    const int bh = blockIdx.y;                 // b*8+h
    const int b = bh >> 3, h = bh & 7;
    const int m0 = blockIdx.x * 128;
    const int tid = threadIdx.x;
    const int wave = tid >> 6, lane = tid & 63;
    const int q = lane >> 4, l16 = lane & 15;

    const u16* Ag; const u16* Bg; int lda, ldb;
    if (mode == 0) {
        Ag = Abase + ((size_t)b * LSEQ + m0) * CDIM + h * 64;  lda = CDIM;
        Bg = Bbase + (size_t)b * 32768 + h * 64;               ldb = CDIM;
    } else {
        Ag = Abase + ((size_t)bh * LSEQ + m0) * 64;            lda = 64;
        Bg = Bbase + (size_t)b * 32768 + (size_t)h * 64 * 64;  ldb = 64;
    }

    const int srow = lane >> 2;          // wave-local row 0..15
    const int scol = (lane & 3) * 8;
    #pragma unroll
    for (int half = 0; half < 2; ++half) {
        #pragma unroll
        for (int pass = 0; pass < 2; ++pass) {
            int row = pass * 64 + wave * 16 + srow;
            gll16(Ag + (size_t)row * lda + half * 32 + scol,
                  &Aq[half][pass * 64 + wave * 16][0]);
        }
        gll16(Bg + (size_t)(wave * 16 + srow) * ldb + half * 32 + scol,
              &Bk[half][wave * 16][0]);
    }
    __syncthreads();

    f32x4 acc[2][4];
    #pragma unroll
    for (int i = 0; i < 2; ++i)
        #pragma unroll
        for (int j = 0; j < 4; ++j) acc[i][j] = (f32x4){0.f, 0.f, 0.f, 0.f};

    #pragma unroll
    for (int kk = 0; kk < 2; ++kk) {
        bf16x8 af[2], bfr[4];
        #pragma unroll
        for (int i = 0; i < 2; ++i)
            af[i] = *(const bf16x8*)&Aq[kk][wave * 32 + i * 16 + l16][q * 8];
        #pragma unroll
        for (int j = 0; j < 4; ++j)
            bfr[j] = *(const bf16x8*)&Bk[kk][j * 16 + l16][q * 8];
        #pragma unroll
        for (int i = 0; i < 2; ++i)
            #pragma unroll
            for (int j = 0; j < 4; ++j)
                acc[i][j] = __builtin_amdgcn_mfma_f32_16x16x32_bf16(af[i], bfr[j], acc[i][j], 0, 0, 0);
    }

    #pragma unroll
    for (int i = 0; i < 2; ++i) {
        int row = m0 + wave * 32 + i * 16 + q * 4;
        #pragma unroll
        for (int j = 0; j < 4; ++j) {
            int col = j * 16 + l16;
            #pragma unroll
            for (int r = 0; r < 4; ++r) {
                if (mode == 0) {
                    outp[((size_t)bh * LSEQ + row + r) * 64 + col] =
                        f2bu(0.125f * acc[i][j][r]);
                } else {
                    outp[((size_t)b * LSEQ + row + r) * CDIM + h * 64 + col] =
                        f2bu(acc[i][j][r]);
                }
            }
        }
    }
}

// ---------------------------------------------------------------------------
// Softmax over L (axis=1) per (b,p) + inclusive prefix scan -> cumT (B,L+1,P)
// Also emits pAT (B,P,L) bf16 for the MFMA pooling GEMM (contiguous write).
// ---------------------------------------------------------------------------
__global__ __launch_bounds__(256) void k_softscan(
    const float* __restrict__ psc, const int* __restrict__ maskPAD,
    u16* __restrict__ pAT, float* __restrict__ cumT)
{
    const int b = blockIdx.x >> 6;
    const int p = blockIdx.x & 63;
    const int tid = threadIdx.x;
    __shared__ float s0[1024], s1[1024];
    __shared__ float redA[4], redB[4];

    float acc[4];
    #pragma unroll
    for (int r = 0; r < 4; ++r) {
        int m = tid + r * 256;
        float a = psc[((size_t)b * LSEQ + m) * PDIM + p];
        if (maskPAD[(size_t)b * LSEQ * LSEQ + m] == 0) a = -32768.0f;
        acc[r] = a;
    }
    float mx = fmaxf(fmaxf(acc[0], acc[1]), fmaxf(acc[2], acc[3]));
    mx = wmax(mx);
    if ((tid & 63) == 0) redA[tid >> 6] = mx;
    __syncthreads();
    mx = fmaxf(fmaxf(redA[0], redA[1]), fmaxf(redA[2], redA[3]));

    float e[4], ls = 0.f;
    #pragma unroll
    for (int r = 0; r < 4; ++r) { e[r] = expf(acc[r] - mx); ls += e[r]; }
    ls = wsum(ls);
    if ((tid & 63) == 0) redB[tid >> 6] = ls;
    __syncthreads();
    float inv = 1.0f / (redB[0] + redB[1] + redB[2] + redB[3]);

    #pragma unroll
    for (int r = 0; r < 4; ++r) {
        int m = tid + r * 256;
        float pa = e[r] * inv;
        pAT[((size_t)b * PDIM + p) * LSEQ + m] = f2bu(pa);
        s0[m] = pa;
    }
    __syncthreads();

    float* src = s0; float* dst = s1;
    for (int off = 1; off < 1024; off <<= 1) {
        #pragma unroll
        for (int r = 0; r < 4; ++r) {
            int i = tid + r * 256;
            float v = src[i];
            if (i >= off) v += src[i - off];
            dst[i] = v;
        }
        __syncthreads();
        float* t = src; src = dst; dst = t;
    }
    size_t cb = (size_t)b * (LSEQ + 1) * PDIM + p;
    if (tid == 0) cumT[cb] = 0.f;
    #pragma unroll
    for (int r = 0; r < 4; ++r) {
        int i = tid + r * 256;
        cumT[cb + (size_t)(i + 1) * PDIM] = src[i];
    }
}

// ---------------------------------------------------------------------------
// Softmax+bias middle kernel: one block per (b,l), 512 threads = (h,p).
// raw is bf16 (B,H,L,P); sc = raw*Kb + bb; wave softmax over p; alpha bf16.
// ---------------------------------------------------------------------------
__global__ __launch_bounds__(512) void k_sm(
    const u16* __restrict__ raw, u16* __restrict__ alb,
    const float* __restrict__ cumT,
    const void* __restrict__ embK, const void* __restrict__ embB,
    const int* __restrict__ flag)
{
    const int fd = flag[0];
    const int b = blockIdx.x >> 10;
    const int l = blockIdx.x & 1023;
    const int tid = threadIdx.x;
    __shared__ float S[15][PDIM];
    __shared__ float eK[120], eB[120];

    if (tid < 120) { eK[tid] = ldDyn(embK, tid, fd); eB[tid] = ldDyn(embB, tid, fd); }

    const float* cb = cumT + (size_t)b * (LSEQ + 1) * PDIM;
    for (int idx = tid; idx < 960; idx += 512) {
        int t = idx >> 6, pp = idx & 63;
        float s;
        if (t == 0) {
            s = cb[(size_t)(l + 1) * 64 + pp] - cb[(size_t)l * 64 + pp];
        } else {
            s = 0.f;
            int hi = l - c_dlo[t];
            int lo = l - c_dhi[t]; if (lo < 0) lo = 0;
            if (hi >= lo) s += cb[(size_t)(hi + 1) * 64 + pp] - cb[(size_t)lo * 64 + pp];
            lo = l + c_dlo[t];
            hi = l + c_dhi[t]; if (hi > 1023) hi = 1023;
            if (lo <= hi) s += cb[(size_t)(hi + 1) * 64 + pp] - cb[(size_t)lo * 64 + pp];
        }
        S[t][pp] = s;
    }
    __syncthreads();

    const int h = tid >> 6, p = tid & 63;   // wave h, lane p
    float kbm = 0.f, bbm = 0.f;
    #pragma unroll
    for (int t = 0; t < 15; ++t) {
        float sv = S[t][p];
        kbm += eK[t * 8 + h] * sv;
        bbm += eB[t * 8 + h] * sv;
    }
    size_t idx = (((size_t)b * 8 + h) * LSEQ + l) * 64 + p;
    float sc = b2f(raw[idx]) * kbm + bbm;
    float mx = wmax(sc);
    float e  = expf(sc - mx);
    float ssum = wsum(e);
    alb[idx] = f2bu(e / ssum);
}

// ---------------------------------------------------------------------------
// Vectorized LayerNorm: 4 rows per block, 128 lanes/row (= 2 full waves),
// 4 consecutive elems per lane (float4/ushort4 loads -- G13).
// y = LN(a (+ badd)) * g + be
// ---------------------------------------------------------------------------
__global__ __launch_bounds__(512) void k_ln4(
    const void* __restrict__ a, const u16* __restrict__ badd,
    const void* __restrict__ g, const void* __restrict__ be, const int* __restrict__ flag,
    void* __restrict__ out, int aKind, int outKind)
{
    const int fd = flag[0];
    const int fA = (aKind == 2) ? fd : aKind;
    const int fO = (outKind == 2) ? fd : outKind;
    const int tid = threadIdx.x;
    const int sub = tid >> 7;             // row within block (0..3)
    const int ln  = tid & 127;            // lane within row
    const size_t row  = (size_t)blockIdx.x * 4 + sub;
    const size_t base = row * CDIM + ln * 4;

    float x[4];
    ld4Dyn(a, base, fA, x);
    if (badd) {
        ushort4 u = *(const ushort4*)&badd[base];
        x[0] += b2f(u.x); x[1] += b2f(u.y); x[2] += b2f(u.z); x[3] += b2f(u.w);
    }

    __shared__ float r1[8], r2[8];        // per-wave partials (8 waves)
    const int wv = tid >> 6;
    float s = wsum(x[0] + x[1] + x[2] + x[3]);
    if ((tid & 63) == 0) r1[wv] = s;
    __syncthreads();
    float mu = (r1[sub * 2] + r1[sub * 2 + 1]) * (1.0f / 512.0f);

    float dv[4], s2 = 0.f;
    #pragma unroll
    for (int k = 0; k < 4; ++k) { dv[k] = x[k] - mu; s2 += dv[k] * dv[k]; }
    s2 = wsum(s2);
    if ((tid & 63) == 0) r2[wv] = s2;
    __syncthreads();
    float inv = rsqrtf((r2[sub * 2] + r2[sub * 2 + 1]) * (1.0f / 512.0f) + 1e-5f);

    float gg[4], bb[4];
    ld4Dyn(g,  (size_t)ln * 4, fd, gg);
    ld4Dyn(be, (size_t)ln * 4, fd, bb);

    float y[4];
    #pragma unroll
    for (int k = 0; k < 4; ++k) y[k] = dv[k] * inv * gg[k] + bb[k];

    if (fO) {
        float4 o; o.x = y[0]; o.y = y[1]; o.z = y[2]; o.w = y[3];
        *(float4*)((float*)out + base) = o;
    } else {
        ushort4 o; o.x = f2bu(y[0]); o.y = f2bu(y[1]); o.z = f2bu(y[2]); o.w = f2bu(y[3]);
        *(ushort4*)((u16*)out + base) = o;
    }
}

// ---------------------------------------------------------------------------
extern "C" void kernel_launch(void* const* d_in, const int* in_sizes, int n_in,
                              void* d_out, int out_size, void* d_ws, size_t ws_size,
                              hipStream_t stream)
{
    (void)in_sizes; (void)n_in; (void)out_size; (void)ws_size;
    const void* qx   = d_in[0];
    const void* kx   = d_in[1];
    const void* vx   = d_in[2];
    const int*  mask = (const int*)d_in[3];
    const void* Wp   = d_in[4];
    const void* bp   = d_in[5];
    const void* WQ   = d_in[6];
    const void* bQ   = d_in[7];
    const void* WK   = d_in[8];
    const void* bK   = d_in[9];
    const void* WV   = d_in[10];
    const void* bV   = d_in[11];
    const void* WO   = d_in[12];
    const void* bO   = d_in[13];
    const void* embK = d_in[14];
    const void* embB = d_in[15];
    const void* l1g  = d_in[16];
    const void* l1b  = d_in[17];
    const void* l2g  = d_in[18];
    const void* l2b  = d_in[19];
    const void* W1   = d_in[20];
    const void* b1   = d_in[21];
    const void* W2   = d_in[22];
    const void* b2   = d_in[23];

    // workspace map (f32-element offsets); end = 30,949,440 slots ~ 123.8 MB
    float* ws     = (float*)d_ws;
    int*   flag   = (int*)d_ws;
    u16*   outFb  = (u16*)(ws + 64);               // 8,388,608 u16 (pre-LN2 bf16)
    float* psc    = ws + 64;                       // 1,048,576 f32 (pScore; dead early)
    float* cumT   = ws + 1048640;                  // 1,049,600 f32 (B,L+1,P)
    u16*   pAT    = (u16*)(ws + 2098240);          // 1,048,576 u16 (B,P,L)
    u16*   kbh    = (u16*)(ws + 2622528);          //   524,288 u16 (B,P,C)
    u16*   vbT    = (u16*)(ws + 2884672);          //   524,288 u16 (B,C,P)
    u16*   albuf  = (u16*)(ws + 3146816);          // 8,388,608 u16 (B,H,L,P)
    u16*   kvxb   = (u16*)(ws + 7341120);          // 1,048,576 u16 (kxp|vxp)
    u16*   qz     = (u16*)(ws + 8388672);          // 8,388,608 u16 (q -> z -> z1)
    u16*   hidden = (u16*)(ws + 12582976);         // 33,554,432 u16 [16384][2048]
    u16*   qxb    = hidden;                        // alias (qx bf16, later zo)
    u16*   zo     = qxb;
    u16*   vxb    = (u16*)(ws + 16777280);         // 8,388,608 u16 (vx bf16)
    u16*   kxT    = (u16*)(ws + 20971584);         // 8,388,608 u16 (B,C,L)
    u16*   vxT    = (u16*)(ws + 25165888);         // 8,388,608 u16 (B,C,L)
    u16*   rawb   = (u16*)(ws + 20971584);         // bf16 (B,H,L,P); kxT dead by then
    u16*   WqT    = (u16*)(ws + 29360192);         // 262,144 u16
    u16*   WkT    = (u16*)(ws + 29491264);
    u16*   WvT    = (u16*)(ws + 29622336);
    u16*   WoT    = (u16*)(ws + 29753408);
    u16*   W1T    = (u16*)(ws + 29884480);         // 1,048,576 u16 [2048][512]
    u16*   W2T    = (u16*)(ws + 30408768);         // 1,048,576 u16 [512][2048]
    u16*   WpT    = (u16*)(ws + 30933056);         //    32,768 u16 [64][512]

    const int MROW = BI * LSEQ;                    // 16384

    // 0) dtype detect; fused converts; weight transposes
    k_detect<<<dim3(1), dim3(256), 0, stream>>>((const unsigned int*)qx, flag);
    k_cvt2<<<dim3(MROW * CDIM / 1024, 2), dim3(256), 0, stream>>>(
        qx, qxb, vx, vxb, flag, MROW * CDIM);
    k_transp4<<<dim3(16, 16, 4), dim3(256), 0, stream>>>(
        WQ, WqT, WK, WkT, WV, WvT, WO, WoT, flag);
    k_transp<<<dim3(2, 16),  dim3(256), 0, stream>>>(Wp, WpT, flag, 512, 64);
    k_transp<<<dim3(64, 16), dim3(256), 0, stream>>>(W1, W1T, flag, 512, 2048);
    k_transp<<<dim3(16, 64), dim3(256), 0, stream>>>(W2, W2T, flag, 2048, 512);
    // 0b) activation transposes for MFMA pooling: kx (dyn), vxb -> (B,C,L) bf16
    k_transpcv<<<dim3(16, 16, 32), dim3(256), 0, stream>>>(kx, vxb, kxT, vxT, flag);

    // 1) pScore = vx @ Wp + bp -> psc (f32)
    gemm_mfma64<<<dim3(1, MROW / 128), dim3(256), 0, stream>>>(
        vxb, WpT, bp, psc, flag, CDIM, CDIM, CDIM);
    // 2) softmax over L + prefix scan -> pAT (bf16, transposed), cumT
    k_softscan<<<dim3(BI * PDIM), dim3(256), 0, stream>>>(psc, mask, pAT, cumT);
    // 3) MFMA pooling -> kvxb bf16 directly (kxp | vxp)
    gemm_pool<<<dim3(4, 16, 2), dim3(256), 0, stream>>>(pAT, kxT, vxT, kvxb);
    // 4) merged projections: q -> qz; k -> kbh (plain) & v -> vbT (perm)
    gemm_qkv<<<dim3(2, 144), dim3(512), 0, stream>>>(
        qxb, WqT, bQ, qz,
        kvxb, kvxb + 524288, WkT, WvT, bK, bV, kbh, vbT, flag);
    // 5) attention: raw = bf16(0.125*q@k^T) -> softmax+bias -> z = alpha@v
    gemm_att<<<dim3(8, BI * HH), dim3(256), 0, stream>>>(qz, kbh, rawb, 0);
    k_sm<<<dim3(BI * LSEQ), dim3(512), 0, stream>>>(
        rawb, albuf, cumT, embK, embB, flag);
    gemm_att<<<dim3(8, BI * HH), dim3(256), 0, stream>>>(albuf, vbT, qz, 1);
    // 6) zo = z @ WO + bO (bf16, into qxb alias)
    gemm_mfma<<<dim3(2, MROW / 128), dim3(512), 0, stream>>>(
        qz, WoT, bO, nullptr, zo, flag, CDIM, CDIM, CDIM, CDIM, 0, 0, 1, 0);
    // 7) LN1: z1 = LN(vx + zo) -> qz (bf16)
    k_ln4<<<dim3(MROW / 4), dim3(512), 0, stream>>>(
        vx, zo, l1g, l1b, flag, qz, 2, 0);
    // 8) FFN, un-chunked: hidden = gelu(z1@W1+b1); outFb = bf16(hidden@W2+b2+z1)
    gemm_mfma<<<dim3(8, MROW / 128), dim3(512), 0, stream>>>(
        qz, W1T, b1, nullptr, hidden, flag, CDIM, CDIM, CDIM, 2048, 0, 1, 1, 0);
    gemm_mfma<<<dim3(2, MROW / 128), dim3(512), 0, stream>>>(
        hidden, W2T, b2, qz, outFb, flag, 2048, 2048, 2048, CDIM, 0, 2, 1, 0);
    // 9) LN2 -> d_out (dtype follows detection)
    k_ln4<<<dim3(MROW / 4), dim3(512), 0, stream>>>(
        outFb, nullptr, l2g, l2b, flag, d_out, 0, 2);
}

// Round 13
// 574.501 us; speedup vs baseline: 1.0266x; 1.0266x over previous
//
#include <hip/hip_runtime.h>
#include <hip/hip_bf16.h>

// Shapes (fixed): B=16, L=1024, C=512, P=64, H=8, DK=64, MRD=7
#define BI   16
#define LSEQ 1024
#define CDIM 512
#define PDIM 64
#define HH   8
#define DKK  64

typedef __hip_bfloat16 bf16;
typedef unsigned short u16;
typedef __attribute__((ext_vector_type(8))) short bf16x8;
typedef __attribute__((ext_vector_type(4))) float f32x4;

// rel-pos bucket boundaries: bucket t covers |l-m| in [dlo[t], dhi[t]]
__constant__ int c_dlo[15] = {0,1,2,3,4,5,6,7, 9,11,15,23,39, 71,135};
__constant__ int c_dhi[15] = {0,1,2,3,4,5,6,8,10,14,22,38,70,134,1023};

__device__ __forceinline__ float b2f(u16 u) {
    union { unsigned int i; float f; } c; c.i = ((unsigned int)u) << 16; return c.f;
}
__device__ __forceinline__ u16 f2bu(float v) {
    bf16 h = __float2bfloat16(v);
    return *(u16*)&h;
}
// dynamic-dtype loads: f=1 -> fp32, f=0 -> bf16
__device__ __forceinline__ float ldDyn(const void* p, size_t i, int f) {
    return f ? ((const float*)p)[i] : b2f(((const u16*)p)[i]);
}
__device__ __forceinline__ void ld4Dyn(const void* p, size_t i, int f, float* o) {
    if (f) { float4 v = *(const float4*)((const float*)p + i);
             o[0]=v.x; o[1]=v.y; o[2]=v.z; o[3]=v.w; }
    else   { ushort4 u = *(const ushort4*)((const u16*)p + i);
             o[0]=b2f(u.x); o[1]=b2f(u.y); o[2]=b2f(u.z); o[3]=b2f(u.w); }
}

// async global->LDS, 16B/lane; lds base wave-uniform (HW: base + lane*16)
__device__ __forceinline__ void gll16(const u16* g, u16* l) {
    __builtin_amdgcn_global_load_lds(
        (const __attribute__((address_space(1))) unsigned int*)g,
        (__attribute__((address_space(3))) unsigned int*)l,
        16, 0, 0);
}

__device__ __forceinline__ float wsum(float v) {
    #pragma unroll
    for (int o = 32; o; o >>= 1) v += __shfl_xor(v, o, 64);
    return v;
}
__device__ __forceinline__ float wmax(float v) {
    #pragma unroll
    for (int o = 32; o; o >>= 1) v = fmaxf(v, __shfl_xor(v, o, 64));
    return v;
}

// exact-precision gelu: erf via Abramowitz-Stegun 7.1.26 (max abs err 1.5e-7)
__device__ __forceinline__ float gelu_f(float v) {
    float x  = v * 0.70710678118654752f;
    float ax = fabsf(x);
    float t  = __builtin_amdgcn_rcpf(1.0f + 0.3275911f * ax);
    float p  = t * (0.254829592f + t * (-0.284496736f + t * (1.421413741f +
               t * (-1.453152027f + t * 1.061405429f))));
    float e  = __expf(-ax * ax);
    float er = 1.0f - p * e;
    er = (x < 0.0f) ? -er : er;
    return 0.5f * v * (1.0f + er);
}

// ---------------------------------------------------------------------------
// dtype detect: flag 0 = bf16, 1 = fp32
// ---------------------------------------------------------------------------
__global__ void k_detect(const unsigned int* __restrict__ qw, int* __restrict__ flag) {
    __shared__ int cnt;
    if (threadIdx.x == 0) cnt = 0;
    __syncthreads();
    int local = 0;
    for (int i = threadIdx.x; i < 4096; i += 256) {
        float fv = b2f((u16)(qw[i] & 0xFFFFu));
        float af = fabsf(fv);
        if (fv == 0.0f || (af >= 0.0009765625f && af <= 32.0f)) local++;
    }
    atomicAdd(&cnt, local);
    __syncthreads();
    if (threadIdx.x == 0) flag[0] = (cnt >= 2048) ? 0 : 1;
}

// ---------------------------------------------------------------------------
// fused 2-tensor convert -> bf16 flat (y selects pair)
// ---------------------------------------------------------------------------
__global__ __launch_bounds__(256) void k_cvt2(
    const void* __restrict__ s0, u16* __restrict__ d0,
    const void* __restrict__ s1, u16* __restrict__ d1,
    const int* __restrict__ flag, int n)
{
    const int fA = flag[0];
    const void* src = blockIdx.y ? s1 : s0;
    u16* dst = blockIdx.y ? d1 : d0;
    int i = (blockIdx.x * 256 + threadIdx.x) * 4;
    if (i >= n) return;
    float t[4]; ld4Dyn(src, i, fA, t);
    ushort4 o; o.x = f2bu(t[0]); o.y = f2bu(t[1]); o.z = f2bu(t[2]); o.w = f2bu(t[3]);
    *(ushort4*)(dst + i) = o;
}

// ---------------------------------------------------------------------------
// transpose dyn W[Kd][Nd] -> bf16 WT[Nd][Kd]
// ---------------------------------------------------------------------------
__device__ __forceinline__ void transp_core(
    const void* W, u16* WT, int fd, int Kd, int Nd, int bx, int by)
{
    __shared__ u16 t[32][33];
    const int tx = threadIdx.x & 31, ty = threadIdx.x >> 5;   // 32 x 8
    #pragma unroll
    for (int r = 0; r < 32; r += 8) {
        int k = by * 32 + ty + r, n = bx * 32 + tx;
        t[ty + r][tx] = f2bu(ldDyn(W, (size_t)k * Nd + n, fd));
    }
    __syncthreads();
    #pragma unroll
    for (int r = 0; r < 32; r += 8) {
        int n = bx * 32 + ty + r, k = by * 32 + tx;
        WT[(size_t)n * Kd + k] = t[tx][ty + r];
    }
}

__global__ __launch_bounds__(256) void k_transp(
    const void* __restrict__ W, u16* __restrict__ WT, const int* __restrict__ flag,
    int Kd, int Nd)
{
    transp_core(W, WT, flag[0], Kd, Nd, blockIdx.x, blockIdx.y);
}

// fused 4x 512x512 transpose (z selects weight)
__global__ __launch_bounds__(256) void k_transp4(
    const void* __restrict__ W0, u16* __restrict__ T0,
    const void* __restrict__ W1, u16* __restrict__ T1,
    const void* __restrict__ W2, u16* __restrict__ T2,
    const void* __restrict__ W3, u16* __restrict__ T3,
    const int* __restrict__ flag)
{
    const void* W; u16* T;
    switch (blockIdx.z) {
        case 0: W = W0; T = T0; break;
        case 1: W = W1; T = T1; break;
        case 2: W = W2; T = T2; break;
        default: W = W3; T = T3; break;
    }
    transp_core(W, T, flag[0], 512, 512, blockIdx.x, blockIdx.y);
}

// ---------------------------------------------------------------------------
// transpose+convert activations: src (B,L,C) -> dst (B,C,L) bf16
// z<16: kx (dyn dtype); z>=16: vxb (bf16). Tiles: 32 c-rows x 64 l-cols.
// ---------------------------------------------------------------------------
__global__ __launch_bounds__(256) void k_transpcv(
    const void* __restrict__ kx, const u16* __restrict__ vxb,
    u16* __restrict__ kxT, u16* __restrict__ vxT, const int* __restrict__ flag)
{
    const int t = blockIdx.z >> 4;        // 0=k, 1=v
    const int b = blockIdx.z & 15;
    const int l0 = blockIdx.x * 64, c0 = blockIdx.y * 32;
    __shared__ u16 s[32][72];             // [c][l], padded
    const int tid = threadIdx.x;
    if (t == 0) {
        const int fd = flag[0];
        #pragma unroll
        for (int p = 0; p < 2; ++p) {
            int l = (tid >> 3) + p * 32, c4 = (tid & 7) * 4;
            float v[4];
            ld4Dyn(kx, ((size_t)b * LSEQ + l0 + l) * CDIM + c0 + c4, fd, v);
            #pragma unroll
            for (int k = 0; k < 4; ++k) s[c4 + k][l] = f2bu(v[k]);
        }
    } else {
        #pragma unroll
        for (int p = 0; p < 2; ++p) {
            int l = (tid >> 3) + p * 32, c4 = (tid & 7) * 4;
            ushort4 u = *(const ushort4*)&vxb[((size_t)b * LSEQ + l0 + l) * CDIM + c0 + c4];
            s[c4 + 0][l] = u.x; s[c4 + 1][l] = u.y;
            s[c4 + 2][l] = u.z; s[c4 + 3][l] = u.w;
        }
    }
    __syncthreads();
    u16* dst = t ? vxT : kxT;
    #pragma unroll
    for (int p = 0; p < 2; ++p) {
        int c = (tid >> 4) + p * 16, l4 = (tid & 15) * 4;
        *(ushort4*)&dst[((size_t)b * CDIM + c0 + c) * LSEQ + l0 + l4] =
            *(const ushort4*)&s[c][l4];
    }
}

// ---------------------------------------------------------------------------
// MFMA bf16 GEMM core: 128m x 256n tile, BK=32, 8 waves (512 thr), each wave
// a 64x64 sub-tile (4x4 16x16x32 frags). 2-buf, counted vmcnt (T4), two
// barriers per K-step (R7/R9/R11-verified schedule):
//   iter t: stage(t+1) [3 gll16/lane] -> vmcnt(3) [tile t landed, t+1 in
//   flight] -> s_barrier -> ds_read+MFMA buf t&1 -> lgkmcnt(0)+s_barrier.
// LDS 48 KB -> 3 blocks/CU @ 512 thr.
// T2 swizzle (verified conflict-free in R4): LDS chunk c (16B) of row r holds
// global chunk c ^ ((r%16)>>1 & 3); stage source col =
// ((lane&3)^((lane>>3)&3))*8; read chunk = q ^ ((l16>>1)&3).
// Epilogue: bias hoisted to 4 loads/thread; gelu via gelu_f.
// mode 0: C = acc+bias ; 1: C = gelu(acc+bias) ;
// mode 2: C = acc + bias + bf16 residual res[m*ldc+col] (outBf selects dtype)
// perm=1 (modes 0/1): write at ((m>>6)<<15)+(col<<6)+(m&63)
// ---------------------------------------------------------------------------
__device__ __forceinline__ void gemm_core(
    u16 (*As)[32], u16 (*Bs)[32],
    const u16* A, const u16* BT, const void* bias, const u16* res, void* Cc, int fd,
    int K, int lda, int ldbt, int ldc, size_t bOff, int mode, int outBf, int perm,
    int m0, int n0)
{
    const int tid = threadIdx.x;
    const int wave = tid >> 6, lane = tid & 63;
    const int q = lane >> 4, l16 = lane & 15;
    const int wm = (wave >> 2) * 64, wn = (wave & 3) * 64;
    const int srow = lane >> 2;
    const int scol = ((lane & 3) ^ ((lane >> 3) & 3)) * 8;   // swizzled source col
    const int rchk = (l16 >> 1) & 3;                          // read-side XOR
    const int nt = K >> 5;

    f32x4 acc[4][4];
    #pragma unroll
    for (int i = 0; i < 4; ++i)
        #pragma unroll
        for (int j = 0; j < 4; ++j) acc[i][j] = (f32x4){0.f, 0.f, 0.f, 0.f};

    // 3 gll16 per lane per stage call (A: 128 rows = 1; B: 256 rows = 2)
    auto stage = [&](int t, int buf) {
        gll16(A + (size_t)(m0 + wave * 16 + srow) * lda + t * 32 + scol,
              &As[buf * 128 + wave * 16][0]);
        #pragma unroll
        for (int pass = 0; pass < 2; ++pass)
            gll16(BT + (size_t)(n0 + pass * 128 + wave * 16 + srow) * ldbt + t * 32 + scol,
                  &Bs[buf * 256 + pass * 128 + wave * 16][0]);
    };

    stage(0, 0);

    for (int t = 0; t < nt; ++t) {
        if (t + 1 < nt) {
            stage(t + 1, (t + 1) & 1);
            asm volatile("s_waitcnt vmcnt(3)" ::: "memory");   // tile t landed
        } else {
            asm volatile("s_waitcnt vmcnt(0)" ::: "memory");
        }
        __builtin_amdgcn_sched_barrier(0);
        __builtin_amdgcn_s_barrier();          // all waves: tile t staged

        const int ca = (t & 1) * 128, cbB = (t & 1) * 256;
        bf16x8 af[4], bfr[4];
        #pragma unroll
        for (int i = 0; i < 4; ++i)
            af[i] = *(const bf16x8*)&As[ca + wm + i * 16 + l16][(q ^ rchk) * 8];
        #pragma unroll
        for (int j = 0; j < 4; ++j)
            bfr[j] = *(const bf16x8*)&Bs[cbB + wn + j * 16 + l16][(q ^ rchk) * 8];
        #pragma unroll
        for (int i = 0; i < 4; ++i)
            #pragma unroll
            for (int j = 0; j < 4; ++j)
                acc[i][j] = __builtin_amdgcn_mfma_f32_16x16x32_bf16(af[i], bfr[j], acc[i][j], 0, 0, 0);

        if (t + 1 < nt) {
            // my ds_reads of buf t are complete -> safe for all to restage it
            asm volatile("s_waitcnt lgkmcnt(0)" ::: "memory");
            __builtin_amdgcn_sched_barrier(0);
            __builtin_amdgcn_s_barrier();
        }
    }

    // hoisted bias: depends only on (j, l16)
    float bv[4];
    #pragma unroll
    for (int j = 0; j < 4; ++j)
        bv[j] = ldDyn(bias, bOff + (size_t)(n0 + wn + j * 16 + l16), fd);

    #pragma unroll
    for (int i = 0; i < 4; ++i) {
        int row = m0 + wm + i * 16 + q * 4;
        #pragma unroll
        for (int j = 0; j < 4; ++j) {
            int col = n0 + wn + j * 16 + l16;
            #pragma unroll
            for (int r = 0; r < 4; ++r) {
                float v = acc[i][j][r] + bv[j];
                int m = row + r;
                if (mode == 2) {
                    v += b2f(res[(size_t)m * ldc + col]);
                    if (outBf) ((u16*)Cc)[(size_t)m * ldc + col] = f2bu(v);
                    else       ((float*)Cc)[(size_t)m * ldc + col] = v;
                } else {
                    if (mode == 1) v = gelu_f(v);
                    size_t idx = perm ? (size_t)((m >> 6) << 15) + ((size_t)col << 6) + (m & 63)
                                      : (size_t)m * ldc + col;
                    if (outBf) ((u16*)Cc)[idx] = f2bu(v);
                    else       ((float*)Cc)[idx] = v;
                }
            }
        }
    }
}

// XCD-aware bijective swizzle (nwg multiple of 8): each XCD gets a contiguous
// chunk of M-panels so A-panels + weights fit its private L2.
__global__ __launch_bounds__(512) void gemm_mfma(
    const u16* __restrict__ A, const u16* __restrict__ BT, const void* __restrict__ bias,
    const u16* __restrict__ res, void* __restrict__ Cc, const int* __restrict__ flag,
    int K, int lda, int ldbt, int ldc, size_t bOff, int mode, int outBf, int perm)
{
    __shared__ u16 As[256][32];   // 2 x 128-row bufs, 16 KB
    __shared__ u16 Bs[512][32];   // 2 x 256-row bufs, 32 KB
    const int lin = blockIdx.y * gridDim.x + blockIdx.x;
    const int chunk = (gridDim.x * gridDim.y) >> 3;
    const int wg = (lin & 7) * chunk + (lin >> 3);
    const int bx = wg % gridDim.x, by = wg / gridDim.x;
    gemm_core(As, Bs, A, BT, bias, res, Cc, flag[0], K, lda, ldbt, ldc, bOff,
              mode, outBf, perm, by * 128, bx * 256);
}

// ---------------------------------------------------------------------------
// Merged q-projection + k/v projection in ONE launch, grid (2, 144):
//   by <  128 : q-proj (256 blocks, XCD-swizzled over the q-subgrid)
//   by >= 128 : kv (16 blocks: t = by-128; z = t>>3 selects k/v; M-tile = t&7)
// Both paths call the same gemm_core with K=512 -> identical, block-uniform
// barrier structure (branch is on blockIdx only; no divergent barriers).
// ---------------------------------------------------------------------------
__global__ __launch_bounds__(512) void gemm_qkv(
    const u16* __restrict__ Aq, const u16* __restrict__ WqT,
    const void* __restrict__ bQ, u16* __restrict__ qz,
    const u16* __restrict__ A0, const u16* __restrict__ A1,
    const u16* __restrict__ BT0, const u16* __restrict__ BT1,
    const void* __restrict__ b0, const void* __restrict__ b1,
    void* __restrict__ C0, void* __restrict__ C1,
    const int* __restrict__ flag)
{
    __shared__ u16 As[256][32];
    __shared__ u16 Bs[512][32];
    const int fd = flag[0];
    if (blockIdx.y < 128) {
        const int lin = blockIdx.y * 2 + blockIdx.x;       // 256 q-blocks
        const int wg = (lin & 7) * 32 + (lin >> 3);        // bijective XCD swizzle
        const int bx = wg & 1, by = wg >> 1;
        gemm_core(As, Bs, Aq, WqT, bQ, nullptr, qz, fd,
                  CDIM, CDIM, CDIM, CDIM, 0, 0, 1, 0, by * 128, bx * 256);
    } else {
        const int t = blockIdx.y - 128;                    // 0..15
        const int z = t >> 3, by = t & 7;
        gemm_core(As, Bs, z ? A1 : A0, z ? BT1 : BT0, z ? b1 : b0, nullptr,
                  z ? C1 : C0, fd,
                  CDIM, CDIM, CDIM, CDIM, 0, 0, 1, z ? 1 : 0,
                  by * 128, blockIdx.x * 256);
    }
}

// ---------------------------------------------------------------------------
// MFMA pooling: out[b,p,c] = sum_l pAT[b,p,l] * T[b,c,l]; bf16 out into kvxb.
// M=64 (P), N-tile=128 over C, K=L=1024. Double-buffered.
// ---------------------------------------------------------------------------
__global__ __launch_bounds__(256) void gemm_pool(
    const u16* __restrict__ pAT, const u16* __restrict__ kxT,
    const u16* __restrict__ vxT, u16* __restrict__ kvxb)
{
    __shared__ u16 As[128][32];    // 2 x 64-row bufs
    __shared__ u16 Bs[256][32];    // 2 x 128-row bufs
    const int b = blockIdx.y;
    const int n0 = blockIdx.x * 128;
    const u16* Ag = pAT + (size_t)b * (PDIM * LSEQ);
    const u16* Bg = (blockIdx.z ? vxT : kxT) + (size_t)b * (CDIM * LSEQ);
    u16* Cg = kvxb + (size_t)blockIdx.z * 524288 + (size_t)b * (PDIM * CDIM);

    const int tid = threadIdx.x;
    const int wave = tid >> 6, lane = tid & 63;
    const int q = lane >> 4, l16 = lane & 15;
    const int wm = (wave >> 1) * 32, wn = (wave & 1) * 64;
    const int srow = lane >> 2, scol = (lane & 3) * 8;

    f32x4 acc[2][4];
    #pragma unroll
    for (int i = 0; i < 2; ++i)
        #pragma unroll
        for (int j = 0; j < 4; ++j) acc[i][j] = (f32x4){0.f, 0.f, 0.f, 0.f};

    gll16(Ag + (size_t)(wave * 16 + srow) * LSEQ + scol, &As[wave * 16][0]);
    #pragma unroll
    for (int pass = 0; pass < 2; ++pass)
        gll16(Bg + (size_t)(n0 + wave * 32 + pass * 16 + srow) * LSEQ + scol,
              &Bs[wave * 32 + pass * 16][0]);
    __syncthreads();

    int cur = 0;
    for (int k0 = 0; k0 < LSEQ; k0 += 32) {
        if (k0 + 32 < LSEQ) {
            const int na = (cur ^ 1) * 64, nb = (cur ^ 1) * 128;
            gll16(Ag + (size_t)(wave * 16 + srow) * LSEQ + (k0 + 32) + scol,
                  &As[na + wave * 16][0]);
            #pragma unroll
            for (int pass = 0; pass < 2; ++pass)
                gll16(Bg + (size_t)(n0 + wave * 32 + pass * 16 + srow) * LSEQ + (k0 + 32) + scol,
                      &Bs[nb + wave * 32 + pass * 16][0]);
        }
        const int ca = cur * 64, cb = cur * 128;
        bf16x8 af[2], bfr[4];
        #pragma unroll
        for (int i = 0; i < 2; ++i) af[i] = *(const bf16x8*)&As[ca + wm + i * 16 + l16][q * 8];
        #pragma unroll
        for (int j = 0; j < 4; ++j) bfr[j] = *(const bf16x8*)&Bs[cb + wn + j * 16 + l16][q * 8];
        #pragma unroll
        for (int i = 0; i < 2; ++i)
            #pragma unroll
            for (int j = 0; j < 4; ++j)
                acc[i][j] = __builtin_amdgcn_mfma_f32_16x16x32_bf16(af[i], bfr[j], acc[i][j], 0, 0, 0);
        __syncthreads();
        cur ^= 1;
    }

    #pragma unroll
    for (int i = 0; i < 2; ++i) {
        int row = wm + i * 16 + q * 4;
        #pragma unroll
        for (int j = 0; j < 4; ++j) {
            int col = n0 + wn + j * 16 + l16;
            #pragma unroll
            for (int r = 0; r < 4; ++r)
                Cg[(size_t)(row + r) * CDIM + col] = f2bu(acc[i][j][r]);
        }
    }
}

// ---------------------------------------------------------------------------
// MFMA bf16 GEMM, 128m x 64n tile (pScore): C = A @ BT^T + bias, f32, ldc=64
// Double-buffered.
// ---------------------------------------------------------------------------
__global__ __launch_bounds__(256) void gemm_mfma64(
    const u16* __restrict__ A, const u16* __restrict__ BT, const void* __restrict__ bias,
    float* __restrict__ Cc, const int* __restrict__ flag,
    int K, int lda, int ldbt)
{
    const int fd = flag[0];
    __shared__ u16 As[256][32];    // 2 x 128-row bufs
    __shared__ u16 Bs[128][32];    // 2 x 64-row bufs
    const int m0 = blockIdx.y * 128;
    const int tid = threadIdx.x;
    const int wave = tid >> 6, lane = tid & 63;
    const int q = lane >> 4, l16 = lane & 15;
    const int wm = wave * 32;
    const int srow = wave * 16 + (lane >> 2);
    const int scol = (lane & 3) * 8;

    f32x4 acc[2][4];
    #pragma unroll
    for (int i = 0; i < 2; ++i)
        #pragma unroll
        for (int j = 0; j < 4; ++j) acc[i][j] = (f32x4){0.f, 0.f, 0.f, 0.f};

    #pragma unroll
    for (int pass = 0; pass < 2; ++pass) {
        int row = pass * 64 + srow;
        gll16(A + (size_t)(m0 + row) * lda + scol, &As[pass * 64 + wave * 16][0]);
    }
    gll16(BT + (size_t)srow * ldbt + scol, &Bs[wave * 16][0]);
    __syncthreads();

    int cur = 0;
    for (int k0 = 0; k0 < K; k0 += 32) {
        if (k0 + 32 < K) {
            const int na = (cur ^ 1) * 128, nb = (cur ^ 1) * 64;
            #pragma unroll
            for (int pass = 0; pass < 2; ++pass) {
                int row = pass * 64 + srow;
                gll16(A + (size_t)(m0 + row) * lda + (k0 + 32) + scol,
                      &As[na + pass * 64 + wave * 16][0]);
            }
            gll16(BT + (size_t)srow * ldbt + (k0 + 32) + scol, &Bs[nb + wave * 16][0]);
        }
        const int ca = cur * 128, cb = cur * 64;
        bf16x8 af[2], bfr[4];
        #pragma unroll
        for (int i = 0; i < 2; ++i) af[i] = *(const bf16x8*)&As[ca + wm + i * 16 + l16][q * 8];
        #pragma unroll
        for (int j = 0; j < 4; ++j) bfr[j] = *(const bf16x8*)&Bs[cb + j * 16 + l16][q * 8];
        #pragma unroll
        for (int i = 0; i < 2; ++i)
            #pragma unroll
            for (int j = 0; j < 4; ++j)
                acc[i][j] = __builtin_amdgcn_mfma_f32_16x16x32_bf16(af[i], bfr[j], acc[i][j], 0, 0, 0);
        __syncthreads();
        cur ^= 1;
    }

    #pragma unroll
    for (int i = 0; i < 2; ++i) {
        int row = m0 + wm + i * 16 + q * 4;
        #pragma unroll
        for (int j = 0; j < 4; ++j) {
            int col = j * 16 + l16;
            #pragma unroll
            for (int r = 0; r < 4; ++r)
                Cc[(size_t)(row + r) * 64 + col] = acc[i][j][r] + ldDyn(bias, col, fd);
        }
    }
}

// ---------------------------------------------------------------------------
// Attention GEMMs, batched per (b,h): 128m x 64n, K=64, 4 waves stacked in m.
// mode 0: raw[bh,l,p] = bf16(0.125 * q_h @ k_h^T)  (A=qz lda=512, B=kbh ldb=512)
// mode 1: z[b,l,h*64+d] = alpha_h @ v_h^T          (A=albuf lda=64, B=vbT ldb=64)
// ---------------------------------------------------------------------------
__global__ __launch_bounds__(256) void gemm_att(
    const u16* __restrict__ Abase, const u16* __restrict__ Bbase,
    u16* __restrict__ outp, int mode)
{
    __shared__ u16 Aq[2][128][32];   // [k-half][l][k] 16 KB
    __shared__ u16 Bk[2][64][32];    // 8 KB
    const int bh = blockIdx.y;                 // b*8+h
    const int b = bh >> 3, h = bh & 7;
    const int m0 = blockIdx.x * 128;
    const int tid = threadIdx.x;
    const int wave = tid >> 6, lane = tid & 63;
    const int q = lane >> 4, l16 = lane & 15;

    const u16* Ag; const u16* Bg; int lda, ldb;
    if (mode == 0) {
        Ag = Abase + ((size_t)b * LSEQ + m0) * CDIM + h * 64;  lda = CDIM;
        Bg = Bbase + (size_t)b * 32768 + h * 64;               ldb = CDIM;
    } else {
        Ag = Abase + ((size_t)bh * LSEQ + m0) * 64;            lda = 64;
        Bg = Bbase + (size_t)b * 32768 + (size_t)h * 64 * 64;  ldb = 64;
    }

    const int srow = lane >> 2;          // wave-local row 0..15
    const int scol = (lane & 3) * 8;
    #pragma unroll
    for (int half = 0; half < 2; ++half) {
        #pragma unroll
        for (int pass = 0; pass < 2; ++pass) {
            int row = pass * 64 + wave * 16 + srow;
            gll16(Ag + (size_t)row * lda + half * 32 + scol,
                  &Aq[half][pass * 64 + wave * 16][0]);
        }
        gll16(Bg + (size_t)(wave * 16 + srow) * ldb + half * 32 + scol,
              &Bk[half][wave * 16][0]);
    }
    __syncthreads();

    f32x4 acc[2][4];
    #pragma unroll
    for (int i = 0; i < 2; ++i)
        #pragma unroll
        for (int j = 0; j < 4; ++j) acc[i][j] = (f32x4){0.f, 0.f, 0.f, 0.f};

    #pragma unroll
    for (int kk = 0; kk < 2; ++kk) {
        bf16x8 af[2], bfr[4];
        #pragma unroll
        for (int i = 0; i < 2; ++i)
            af[i] = *(const bf16x8*)&Aq[kk][wave * 32 + i * 16 + l16][q * 8];
        #pragma unroll
        for (int j = 0; j < 4; ++j)
            bfr[j] = *(const bf16x8*)&Bk[kk][j * 16 + l16][q * 8];
        #pragma unroll
        for (int i = 0; i < 2; ++i)
            #pragma unroll
            for (int j = 0; j < 4; ++j)
                acc[i][j] = __builtin_amdgcn_mfma_f32_16x16x32_bf16(af[i], bfr[j], acc[i][j], 0, 0, 0);
    }

    #pragma unroll
    for (int i = 0; i < 2; ++i) {
        int row = m0 + wave * 32 + i * 16 + q * 4;
        #pragma unroll
        for (int j = 0; j < 4; ++j) {
            int col = j * 16 + l16;
            #pragma unroll
            for (int r = 0; r < 4; ++r) {
                if (mode == 0) {
                    outp[((size_t)bh * LSEQ + row + r) * 64 + col] =
                        f2bu(0.125f * acc[i][j][r]);
                } else {
                    outp[((size_t)b * LSEQ + row + r) * CDIM + h * 64 + col] =
                        f2bu(acc[i][j][r]);
                }
            }
        }
    }
}

// ---------------------------------------------------------------------------
// Softmax over L (axis=1) per (b,p) + inclusive prefix scan -> cumT (B,L+1,P)
// Also emits pAT (B,P,L) bf16 for the MFMA pooling GEMM (contiguous write).
// ---------------------------------------------------------------------------
__global__ __launch_bounds__(256) void k_softscan(
    const float* __restrict__ psc, const int* __restrict__ maskPAD,
    u16* __restrict__ pAT, float* __restrict__ cumT)
{
    const int b = blockIdx.x >> 6;
    const int p = blockIdx.x & 63;
    const int tid = threadIdx.x;
    __shared__ float s0[1024], s1[1024];
    __shared__ float redA[4], redB[4];

    float acc[4];
    #pragma unroll
    for (int r = 0; r < 4; ++r) {
        int m = tid + r * 256;
        float a = psc[((size_t)b * LSEQ + m) * PDIM + p];
        if (maskPAD[(size_t)b * LSEQ * LSEQ + m] == 0) a = -32768.0f;
        acc[r] = a;
    }
    float mx = fmaxf(fmaxf(acc[0], acc[1]), fmaxf(acc[2], acc[3]));
    mx = wmax(mx);
    if ((tid & 63) == 0) redA[tid >> 6] = mx;
    __syncthreads();
    mx = fmaxf(fmaxf(redA[0], redA[1]), fmaxf(redA[2], redA[3]));

    float e[4], ls = 0.f;
    #pragma unroll
    for (int r = 0; r < 4; ++r) { e[r] = expf(acc[r] - mx); ls += e[r]; }
    ls = wsum(ls);
    if ((tid & 63) == 0) redB[tid >> 6] = ls;
    __syncthreads();
    float inv = 1.0f / (redB[0] + redB[1] + redB[2] + redB[3]);

    #pragma unroll
    for (int r = 0; r < 4; ++r) {
        int m = tid + r * 256;
        float pa = e[r] * inv;
        pAT[((size_t)b * PDIM + p) * LSEQ + m] = f2bu(pa);
        s0[m] = pa;
    }
    __syncthreads();

    float* src = s0; float* dst = s1;
    for (int off = 1; off < 1024; off <<= 1) {
        #pragma unroll
        for (int r = 0; r < 4; ++r) {
            int i = tid + r * 256;
            float v = src[i];
            if (i >= off) v += src[i - off];
            dst[i] = v;
        }
        __syncthreads();
        float* t = src; src = dst; dst = t;
    }
    size_t cb = (size_t)b * (LSEQ + 1) * PDIM + p;
    if (tid == 0) cumT[cb] = 0.f;
    #pragma unroll
    for (int r = 0; r < 4; ++r) {
        int i = tid + r * 256;
        cumT[cb + (size_t)(i + 1) * PDIM] = src[i];
    }
}

// ---------------------------------------------------------------------------
// Softmax+bias middle kernel: one block per (b,l), 512 threads = (h,p).
// raw is bf16 (B,H,L,P); sc = raw*Kb + bb; wave softmax over p; alpha bf16.
// ---------------------------------------------------------------------------
__global__ __launch_bounds__(512) void k_sm(
    const u16* __restrict__ raw, u16* __restrict__ alb,
    const float* __restrict__ cumT,
    const void* __restrict__ embK, const void* __restrict__ embB,
    const int* __restrict__ flag)
{
    const int fd = flag[0];
    const int b = blockIdx.x >> 10;
    const int l = blockIdx.x & 1023;
    const int tid = threadIdx.x;
    __shared__ float S[15][PDIM];
    __shared__ float eK[120], eB[120];

    if (tid < 120) { eK[tid] = ldDyn(embK, tid, fd); eB[tid] = ldDyn(embB, tid, fd); }

    const float* cb = cumT + (size_t)b * (LSEQ + 1) * PDIM;
    for (int idx = tid; idx < 960; idx += 512) {
        int t = idx >> 6, pp = idx & 63;
        float s;
        if (t == 0) {
            s = cb[(size_t)(l + 1) * 64 + pp] - cb[(size_t)l * 64 + pp];
        } else {
            s = 0.f;
            int hi = l - c_dlo[t];
            int lo = l - c_dhi[t]; if (lo < 0) lo = 0;
            if (hi >= lo) s += cb[(size_t)(hi + 1) * 64 + pp] - cb[(size_t)lo * 64 + pp];
            lo = l + c_dlo[t];
            hi = l + c_dhi[t]; if (hi > 1023) hi = 1023;
            if (lo <= hi) s += cb[(size_t)(hi + 1) * 64 + pp] - cb[(size_t)lo * 64 + pp];
        }
        S[t][pp] = s;
    }
    __syncthreads();

    const int h = tid >> 6, p = tid & 63;   // wave h, lane p
    float kbm = 0.f, bbm = 0.f;
    #pragma unroll
    for (int t = 0; t < 15; ++t) {
        float sv = S[t][p];
        kbm += eK[t * 8 + h] * sv;
        bbm += eB[t * 8 + h] * sv;
    }
    size_t idx = (((size_t)b * 8 + h) * LSEQ + l) * 64 + p;
    float sc = b2f(raw[idx]) * kbm + bbm;
    float mx = wmax(sc);
    float e  = expf(sc - mx);
    float ssum = wsum(e);
    alb[idx] = f2bu(e / ssum);
}

// ---------------------------------------------------------------------------
// Vectorized LayerNorm: 4 rows per block, 128 lanes/row (= 2 full waves),
// 4 consecutive elems per lane (float4/ushort4 loads -- G13).
// y = LN(a (+ badd)) * g + be
// ---------------------------------------------------------------------------
__global__ __launch_bounds__(512) void k_ln4(
    const void* __restrict__ a, const u16* __restrict__ badd,
    const void* __restrict__ g, const void* __restrict__ be, const int* __restrict__ flag,
    void* __restrict__ out, int aKind, int outKind)
{
    const int fd = flag[0];
    const int fA = (aKind == 2) ? fd : aKind;
    const int fO = (outKind == 2) ? fd : outKind;
    const int tid = threadIdx.x;
    const int sub = tid >> 7;             // row within block (0..3)
    const int ln  = tid & 127;            // lane within row
    const size_t row  = (size_t)blockIdx.x * 4 + sub;
    const size_t base = row * CDIM + ln * 4;

    float x[4];
    ld4Dyn(a, base, fA, x);
    if (badd) {
        ushort4 u = *(const ushort4*)&badd[base];
        x[0] += b2f(u.x); x[1] += b2f(u.y); x[2] += b2f(u.z); x[3] += b2f(u.w);
    }

    __shared__ float r1[8], r2[8];        // per-wave partials (8 waves)
    const int wv = tid >> 6;
    float s = wsum(x[0] + x[1] + x[2] + x[3]);
    if ((tid & 63) == 0) r1[wv] = s;
    __syncthreads();
    float mu = (r1[sub * 2] + r1[sub * 2 + 1]) * (1.0f / 512.0f);

    float dv[4], s2 = 0.f;
    #pragma unroll
    for (int k = 0; k < 4; ++k) { dv[k] = x[k] - mu; s2 += dv[k] * dv[k]; }
    s2 = wsum(s2);
    if ((tid & 63) == 0) r2[wv] = s2;
    __syncthreads();
    float inv = rsqrtf((r2[sub * 2] + r2[sub * 2 + 1]) * (1.0f / 512.0f) + 1e-5f);

    float gg[4], bb[4];
    ld4Dyn(g,  (size_t)ln * 4, fd, gg);
    ld4Dyn(be, (size_t)ln * 4, fd, bb);

    float y[4];
    #pragma unroll
    for (int k = 0; k < 4; ++k) y[k] = dv[k] * inv * gg[k] + bb[k];

    if (fO) {
        float4 o; o.x = y[0]; o.y = y[1]; o.z = y[2]; o.w = y[3];
        *(float4*)((float*)out + base) = o;
    } else {
        ushort4 o; o.x = f2bu(y[0]); o.y = f2bu(y[1]); o.z = f2bu(y[2]); o.w = f2bu(y[3]);
        *(ushort4*)((u16*)out + base) = o;
    }
}

// ---------------------------------------------------------------------------
extern "C" void kernel_launch(void* const* d_in, const int* in_sizes, int n_in,
                              void* d_out, int out_size, void* d_ws, size_t ws_size,
                              hipStream_t stream)
{
    (void)in_sizes; (void)n_in; (void)out_size; (void)ws_size;
    const void* qx   = d_in[0];
    const void* kx   = d_in[1];
    const void* vx   = d_in[2];
    const int*  mask = (const int*)d_in[3];
    const void* Wp   = d_in[4];
    const void* bp   = d_in[5];
    const void* WQ   = d_in[6];
    const void* bQ   = d_in[7];
    const void* WK   = d_in[8];
    const void* bK   = d_in[9];
    const void* WV   = d_in[10];
    const void* bV   = d_in[11];
    const void* WO   = d_in[12];
    const void* bO   = d_in[13];
    const void* embK = d_in[14];
    const void* embB = d_in[15];
    const void* l1g  = d_in[16];
    const void* l1b  = d_in[17];
    const void* l2g  = d_in[18];
    const void* l2b  = d_in[19];
    const void* W1   = d_in[20];
    const void* b1   = d_in[21];
    const void* W2   = d_in[22];
    const void* b2   = d_in[23];

    // workspace map (f32-element offsets); end = 30,949,440 slots ~ 123.8 MB
    float* ws     = (float*)d_ws;
    int*   flag   = (int*)d_ws;
    u16*   outFb  = (u16*)(ws + 64);               // 8,388,608 u16 (pre-LN2 bf16)
    float* psc    = ws + 64;                       // 1,048,576 f32 (pScore; dead early)
    float* cumT   = ws + 1048640;                  // 1,049,600 f32 (B,L+1,P)
    u16*   pAT    = (u16*)(ws + 2098240);          // 1,048,576 u16 (B,P,L)
    u16*   kbh    = (u16*)(ws + 2622528);          //   524,288 u16 (B,P,C)
    u16*   vbT    = (u16*)(ws + 2884672);          //   524,288 u16 (B,C,P)
    u16*   albuf  = (u16*)(ws + 3146816);          // 8,388,608 u16 (B,H,L,P)
    u16*   kvxb   = (u16*)(ws + 7341120);          // 1,048,576 u16 (kxp|vxp)
    u16*   qz     = (u16*)(ws + 8388672);          // 8,388,608 u16 (q -> z -> z1)
    u16*   hidden = (u16*)(ws + 12582976);         // 33,554,432 u16 [16384][2048]
    u16*   qxb    = hidden;                        // alias (qx bf16, later zo)
    u16*   zo     = qxb;
    u16*   vxb    = (u16*)(ws + 16777280);         // 8,388,608 u16 (vx bf16)
    u16*   kxT    = (u16*)(ws + 20971584);         // 8,388,608 u16 (B,C,L)
    u16*   vxT    = (u16*)(ws + 25165888);         // 8,388,608 u16 (B,C,L)
    u16*   rawb   = (u16*)(ws + 20971584);         // bf16 (B,H,L,P); kxT dead by then
    u16*   WqT    = (u16*)(ws + 29360192);         // 262,144 u16
    u16*   WkT    = (u16*)(ws + 29491264);
    u16*   WvT    = (u16*)(ws + 29622336);
    u16*   WoT    = (u16*)(ws + 29753408);
    u16*   W1T    = (u16*)(ws + 29884480);         // 1,048,576 u16 [2048][512]
    u16*   W2T    = (u16*)(ws + 30408768);         // 1,048,576 u16 [512][2048]
    u16*   WpT    = (u16*)(ws + 30933056);         //    32,768 u16 [64][512]

    const int MROW = BI * LSEQ;                    // 16384

    // 0) dtype detect; fused converts; weight transposes
    k_detect<<<dim3(1), dim3(256), 0, stream>>>((const unsigned int*)qx, flag);
    k_cvt2<<<dim3(MROW * CDIM / 1024, 2), dim3(256), 0, stream>>>(
        qx, qxb, vx, vxb, flag, MROW * CDIM);
    k_transp4<<<dim3(16, 16, 4), dim3(256), 0, stream>>>(
        WQ, WqT, WK, WkT, WV, WvT, WO, WoT, flag);
    k_transp<<<dim3(2, 16),  dim3(256), 0, stream>>>(Wp, WpT, flag, 512, 64);
    k_transp<<<dim3(64, 16), dim3(256), 0, stream>>>(W1, W1T, flag, 512, 2048);
    k_transp<<<dim3(16, 64), dim3(256), 0, stream>>>(W2, W2T, flag, 2048, 512);
    // 0b) activation transposes for MFMA pooling: kx (dyn), vxb -> (B,C,L) bf16
    k_transpcv<<<dim3(16, 16, 32), dim3(256), 0, stream>>>(kx, vxb, kxT, vxT, flag);

    // 1) pScore = vx @ Wp + bp -> psc (f32)
    gemm_mfma64<<<dim3(1, MROW / 128), dim3(256), 0, stream>>>(
        vxb, WpT, bp, psc, flag, CDIM, CDIM, CDIM);
    // 2) softmax over L + prefix scan -> pAT (bf16, transposed), cumT
    k_softscan<<<dim3(BI * PDIM), dim3(256), 0, stream>>>(psc, mask, pAT, cumT);
    // 3) MFMA pooling -> kvxb bf16 directly (kxp | vxp)
    gemm_pool<<<dim3(4, 16, 2), dim3(256), 0, stream>>>(pAT, kxT, vxT, kvxb);
    // 4) merged projections: q -> qz; k -> kbh (plain) & v -> vbT (perm)
    gemm_qkv<<<dim3(2, 144), dim3(512), 0, stream>>>(
        qxb, WqT, bQ, qz,
        kvxb, kvxb + 524288, WkT, WvT, bK, bV, kbh, vbT, flag);
    // 5) attention: raw = bf16(0.125*q@k^T) -> softmax+bias -> z = alpha@v
    gemm_att<<<dim3(8, BI * HH), dim3(256), 0, stream>>>(qz, kbh, rawb, 0);
    k_sm<<<dim3(BI * LSEQ), dim3(512), 0, stream>>>(
        rawb, albuf, cumT, embK, embB, flag);
    gemm_att<<<dim3(8, BI * HH), dim3(256), 0, stream>>>(albuf, vbT, qz, 1);
    // 6) zo = z @ WO + bO (bf16, into qxb alias)
    gemm_mfma<<<dim3(2, MROW / 128), dim3(512), 0, stream>>>(
        qz, WoT, bO, nullptr, zo, flag, CDIM, CDIM, CDIM, CDIM, 0, 0, 1, 0);
    // 7) LN1: z1 = LN(vx + zo) -> qz (bf16)
    k_ln4<<<dim3(MROW / 4), dim3(512), 0, stream>>>(
        vx, zo, l1g, l1b, flag, qz, 2, 0);
    // 8) FFN, un-chunked: hidden = gelu(z1@W1+b1); outFb = bf16(hidden@W2+b2+z1)
    gemm_mfma<<<dim3(8, MROW / 128), dim3(512), 0, stream>>>(
        qz, W1T, b1, nullptr, hidden, flag, CDIM, CDIM, CDIM, 2048, 0, 1, 1, 0);
    gemm_mfma<<<dim3(2, MROW / 128), dim3(512), 0, stream>>>(
        hidden, W2T, b2, qz, outFb, flag, 2048, 2048, 2048, CDIM, 0, 2, 1, 0);
    // 9) LN2 -> d_out (dtype follows detection)
    k_ln4<<<dim3(MROW / 4), dim3(512), 0, stream>>>(
        outFb, nullptr, l2g, l2b, flag, d_out, 0, 2);
}